// Round 6
// baseline (130.127 us; speedup 1.0000x reference)
//
#include <hip/hip_runtime.h>

#define HH 14
#define WW 14
#define HWSZ 196
#define TT 16
#define CC 256
#define BB 4
#define RR 64
#define NROI 256
#define PP 7
#define PP2 49

typedef short s4v __attribute__((ext_vector_type(4)));
typedef short s8v __attribute__((ext_vector_type(8)));
typedef float f4v __attribute__((ext_vector_type(4)));

__device__ inline ushort f2bf(float f) {
    union { float f; unsigned u; } v; v.f = f;
    unsigned r = v.u + 0x7fffu + ((v.u >> 16) & 1u);
    return (ushort)(r >> 16);
}
__device__ inline float bf2f(ushort u) {
    union { unsigned u; float f; } v; v.u = ((unsigned)u) << 16;
    return v.f;
}

// ---------------- sumsq partials ----------------
__global__ void k_sumsq(const float* __restrict__ base, float* __restrict__ partial) {
    int blk = blockIdx.x;            // bt*8 + cg
    int bt = blk >> 3, cg = blk & 7;
    int hw = threadIdx.x;
    if (hw >= HWSZ) return;
    int b = bt >> 4, t = bt & 15;
    const float* p = base + ((size_t)(b * CC + cg * 32) * TT + t) * HWSZ + hw;
    float s = 0.f;
    #pragma unroll 8
    for (int c = 0; c < 32; ++c) {
        float v = p[(size_t)c * TT * HWSZ];
        s += v * v;
    }
    partial[cg * 12544 + bt * HWSZ + hw] = s;
}

// ---------------- finish: inv = 1/max(sqrt(sum),1e-12) ----------------
__global__ void k_finish_inv(const float* __restrict__ partial, float* __restrict__ inv) {
    int j = blockIdx.x * 256 + threadIdx.x;
    if (j >= 12544) return;
    float s = 0.f;
    #pragma unroll
    for (int cg = 0; cg < 8; ++cg) s += partial[cg * 12544 + j];
    inv[j] = 1.0f / fmaxf(sqrtf(s), 1e-12f);
}

// ---------------- tsum ----------------
__global__ void k_tsum(const float* __restrict__ base, const float* __restrict__ inv,
                       float* __restrict__ tsum) {
    int bc = blockIdx.x;
    int hw = threadIdx.x;
    if (hw >= HWSZ) return;
    int b = bc >> 8;
    const float* p = base + (size_t)bc * TT * HWSZ + hw;
    const float* iv = inv + b * TT * HWSZ + hw;
    float s = 0.f;
    #pragma unroll
    for (int t = 0; t < TT; ++t) s += p[t * HWSZ] * iv[t * HWSZ];
    tsum[(size_t)bc * HWSZ + hw] = s;
}

// ---------------- ROI align (+rois fused); both outputs coalesced ----------------
__global__ void k_roialign(const float* __restrict__ tubes, const float* __restrict__ tsum,
                           float* __restrict__ pooled, float* __restrict__ pooledT,
                           float* __restrict__ rois) {
    __shared__ int sx0[PP], sx1[PP], sy0[PP], sy1[PP];
    __shared__ float sfx[PP], sfy[PP];
    __shared__ int sb;
    int n = blockIdx.x;
    int tid = threadIdx.x;
    if (tid < PP) {
        const float* tb = tubes + n * 7;
        float x1 = tb[1] * 0.0625f, y1 = tb[2] * 0.0625f;
        float x2 = tb[4] * 0.0625f, y2 = tb[5] * 0.0625f;
        float bw = fmaxf(x2 - x1 + 0.0625f, 0.001f) * (1.0f / PP);
        float bh = fmaxf(y2 - y1 + 0.0625f, 0.001f) * (1.0f / PP);
        float ctr = tid + 0.5f;
        float xs = fminf(fmaxf(x1 + ctr * bw, 0.f), (float)(WW - 1));
        float ys = fminf(fmaxf(y1 + ctr * bh, 0.f), (float)(HH - 1));
        float x0f = floorf(xs), y0f = floorf(ys);
        int x0 = (int)x0f, y0 = (int)y0f;
        sx0[tid] = x0; sx1[tid] = min(x0 + 1, WW - 1);
        sy0[tid] = y0; sy1[tid] = min(y0 + 1, HH - 1);
        sfx[tid] = xs - x0f; sfy[tid] = ys - y0f;
        if (tid == 0) sb = (int)tb[0];
    }
    if (tid < TT) {
        const float* tb = tubes + n * 7;
        int t1 = (int)tb[3], t2 = (int)tb[6];
        bool m = (tid >= t1) && (tid <= t2);
        int b = n >> 6;
        float* o = rois + ((size_t)n * TT + tid) * 5;
        o[0] = (float)(b * TT + tid);
        o[1] = m ? tb[1] : 0.f;
        o[2] = m ? tb[2] : 0.f;
        o[3] = m ? tb[4] : 0.f;
        o[4] = m ? tb[5] : 0.f;
    }
    __syncthreads();
    const float* tbase = tsum + (size_t)sb * CC * HWSZ;

    for (int idx = tid; idx < CC * PP2; idx += 256) {
        int c = idx / PP2, bin = idx - (idx / PP2) * PP2;
        int py = bin / PP, px = bin - (bin / PP) * PP;
        const float* tp = tbase + (size_t)c * HWSZ;
        float fx = sfx[px], fy = sfy[py];
        int y0 = sy0[py] * WW, y1 = sy1[py] * WW;
        float v00 = tp[y0 + sx0[px]];
        float v01 = tp[y0 + sx1[px]];
        float v10 = tp[y1 + sx0[px]];
        float v11 = tp[y1 + sx1[px]];
        float v = (1.f - fy) * ((1.f - fx) * v00 + fx * v01)
                + fy        * ((1.f - fx) * v10 + fx * v11);
        pooled[(size_t)n * CC * PP2 + idx] = v * (1.0f / TT);
    }
    for (int idx = tid; idx < PP2 * CC; idx += 256) {
        int bin = idx >> 8, c = idx & 255;
        int py = bin / PP, px = bin - (bin / PP) * PP;
        const float* tp = tbase + (size_t)c * HWSZ;
        float fx = sfx[px], fy = sfy[py];
        int y0 = sy0[py] * WW, y1 = sy1[py] * WW;
        float v00 = tp[y0 + sx0[px]];
        float v01 = tp[y0 + sx1[px]];
        float v10 = tp[y1 + sx0[px]];
        float v11 = tp[y1 + sx1[px]];
        float v = (1.f - fy) * ((1.f - fx) * v00 + fx * v01)
                + fy        * ((1.f - fx) * v10 + fx * v11);
        pooledT[((size_t)n * PP2 + bin) * CC + c] = v * (1.0f / TT);
    }
}

// ---------------- fp32 GEMM (fc2) ----------------
__global__ __launch_bounds__(256) void gemm64(const float* __restrict__ A,
                                              const float* __restrict__ B_,
                                              float* __restrict__ Cp,
                                              int M, int N, int K,
                                              int lda, int ldb, int kChunk) {
    __shared__ float As[16][64];
    __shared__ float Bs[16][68];
    int m0 = blockIdx.x * 64, n0 = blockIdx.y * 64;
    int s = blockIdx.z;
    int k0 = s * kChunk, kend = k0 + kChunk;
    int tid = threadIdx.x;
    int am = tid >> 2, ak = (tid & 3) << 2;
    int bk = tid >> 4, bn = (tid & 15) << 2;
    int tm = tid >> 4, tn = tid & 15;
    float acc[4][4] = {};
    const float* Aptr = A + (size_t)(m0 + am) * lda + ak;
    const float* Bptr = B_ + (size_t)bk * ldb + n0 + bn;

    for (int kk = k0; kk < kend; kk += 16) {
        float4 av = *(const float4*)(Aptr + kk);
        float4 bv = *(const float4*)(Bptr + (size_t)kk * ldb);
        __syncthreads();
        As[ak + 0][am] = av.x;
        As[ak + 1][am] = av.y;
        As[ak + 2][am] = av.z;
        As[ak + 3][am] = av.w;
        *(float4*)&Bs[bk][bn] = bv;
        __syncthreads();
        #pragma unroll
        for (int k = 0; k < 16; ++k) {
            float4 a = *(const float4*)&As[k][tm << 2];
            float4 b = *(const float4*)&Bs[k][tn << 2];
            float a4[4] = {a.x, a.y, a.z, a.w};
            float b4[4] = {b.x, b.y, b.z, b.w};
            #pragma unroll
            for (int i = 0; i < 4; ++i)
                #pragma unroll
                for (int j = 0; j < 4; ++j)
                    acc[i][j] += a4[i] * b4[j];
        }
    }
    float* Cs = Cp + (size_t)s * M * N;
    #pragma unroll
    for (int i = 0; i < 4; ++i) {
        float4 v = make_float4(acc[i][0], acc[i][1], acc[i][2], acc[i][3]);
        *(float4*)&Cs[(size_t)(m0 + (tm << 2) + i) * N + n0 + (tn << 2)] = v;
    }
}

// ---------------- split-K reduce (fp32 part) ----------------
__global__ void k_reduce(const float* __restrict__ part, const float* __restrict__ bias,
                         float* __restrict__ out, int MN, int N, int S, int relu) {
    int idx = blockIdx.x * 256 + threadIdx.x;
    if (idx >= MN) return;
    float s = bias[idx % N];
    for (int i = 0; i < S; ++i) s += part[(size_t)i * MN + idx];
    if (relu) s = fmaxf(s, 0.f);
    out[idx] = s;
}

// ---------------- split-K reduce for fc1 (bf16 part) + bias + relu ----------------
__global__ void k_reduce_bf(const ushort* __restrict__ part, const float* __restrict__ bias,
                            float* __restrict__ out) {
    int idx = blockIdx.x * 256 + threadIdx.x;
    if (idx >= 256 * 2048) return;
    float s = bias[idx & 2047];
    #pragma unroll
    for (int i = 0; i < 8; ++i) s += bf2f(part[(size_t)i * 524288 + idx]);
    out[idx] = fmaxf(s, 0.f);
}

// ---------------- conv 1x1 via MFMA; epilogue writes xb (bf16, k'-permuted fragment layout) ----
// k' = hw*256 + o. xb index: kg=hw*8+(o>>5); [kg][rblk=n>>4][q=(o>>3)&3][fr=n&15][j=o&7].
__global__ __launch_bounds__(512) void conv_mfma(const float* __restrict__ pooledT,
                                                 const float* __restrict__ conv_w,
                                                 const float* __restrict__ conv_b,
                                                 ushort* __restrict__ xb) {
    __shared__ __align__(16) ushort Ab[2][8192];
    __shared__ __align__(16) ushort Bres[8192];
    const int m0 = blockIdx.x * 256, o0 = blockIdx.y * 64;
    const int tid = threadIdx.x;
    const int lane = tid & 63, w = tid >> 6;
    const int wm = w & 3, wn = w >> 2;
    const int fr = lane & 15, fg = lane >> 4;

    for (int ii = tid; ii < 2048; ii += 512) {
        int o_l = ii >> 5, cq = ii & 31;
        const float* s = conv_w + (size_t)(o0 + o_l) * 256 + cq * 8;
        float4 v0 = *(const float4*)s;
        float4 v1 = *(const float4*)(s + 4);
        float vv[8] = {v0.x, v0.y, v0.z, v0.w, v1.x, v1.y, v1.z, v1.w};
        int dbase = (cq >> 2) * 2048 + (o_l >> 4) * 512 + (cq & 3) * 128 + (o_l & 15);
        #pragma unroll
        for (int jc = 0; jc < 8; ++jc) Bres[dbase + jc * 16] = f2bf(vv[jc]);
    }

    int ii0 = tid, ii1 = 512 + tid, ii2 = 1024 + tid, ii3 = 1536 + tid;
    const float* pA0 = pooledT + (size_t)(m0 + (ii0 >> 3)) * 256 + (ii0 & 7) * 4;
    const float* pA1 = pooledT + (size_t)(m0 + (ii1 >> 3)) * 256 + (ii1 & 7) * 4;
    const float* pA2 = pooledT + (size_t)(m0 + (ii2 >> 3)) * 256 + (ii2 & 7) * 4;
    const float* pA3 = pooledT + (size_t)(m0 + (ii3 >> 3)) * 256 + (ii3 & 7) * 4;
#define CDOFF(ii) (((ii >> 3) >> 4) * 512 + ((ii & 7) >> 1) * 128 + ((ii >> 3) & 15) * 8 + (ii & 1) * 4)
    const int do0 = CDOFF(ii0), do1 = CDOFF(ii1), do2 = CDOFF(ii2), do3 = CDOFF(ii3);
#undef CDOFF
    float4 a0_, a1_, a2_, a3_;
#define CONV_LOAD(t) do { a0_ = *(const float4*)(pA0 + (t) * 32); \
                          a1_ = *(const float4*)(pA1 + (t) * 32); \
                          a2_ = *(const float4*)(pA2 + (t) * 32); \
                          a3_ = *(const float4*)(pA3 + (t) * 32); } while (0)
#define W4(dst, v) do { s4v _u; _u[0]=(short)f2bf((v).x); _u[1]=(short)f2bf((v).y); \
                        _u[2]=(short)f2bf((v).z); _u[3]=(short)f2bf((v).w); \
                        *(s4v*)(dst) = _u; } while (0)
#define CONV_WRITE(buf) do { W4(Ab[buf] + do0, a0_); W4(Ab[buf] + do1, a1_); \
                             W4(Ab[buf] + do2, a2_); W4(Ab[buf] + do3, a3_); } while (0)

    CONV_LOAD(0);
    CONV_WRITE(0);
    __syncthreads();

    const int aoff = wm * 2048 + fg * 128 + fr * 8;
    f4v acc[4][2];
    #pragma unroll
    for (int i = 0; i < 4; ++i)
        #pragma unroll
        for (int j = 0; j < 2; ++j) acc[i][j] = (f4v){0.f, 0.f, 0.f, 0.f};

    for (int t = 0; t < 8; ++t) {
        if (t < 7) CONV_LOAD(t + 1);
        const ushort* A = Ab[t & 1];
        s8v a0 = *(const s8v*)(A + aoff);
        s8v a1 = *(const s8v*)(A + aoff + 512);
        s8v a2 = *(const s8v*)(A + aoff + 1024);
        s8v a3 = *(const s8v*)(A + aoff + 1536);
        unsigned bbase = (unsigned)(size_t)(&Bres[0]) + t * 4096 + wn * 2048 + fg * 256 + fr * 2;
        s4v bl0, bh0, bl1, bh1;
        asm volatile("ds_read_b64_tr_b16 %0, %2\n\t"
                     "ds_read_b64_tr_b16 %1, %2 offset:128"
                     : "=v"(bl0), "=v"(bh0) : "v"(bbase));
        asm volatile("ds_read_b64_tr_b16 %0, %2 offset:1024\n\t"
                     "ds_read_b64_tr_b16 %1, %2 offset:1152"
                     : "=v"(bl1), "=v"(bh1) : "v"(bbase));
        asm volatile("s_waitcnt lgkmcnt(0)" ::: "memory");
        __builtin_amdgcn_sched_barrier(0);
        s8v b0, b1;
        b0[0] = bl0[0]; b0[1] = bl0[1]; b0[2] = bl0[2]; b0[3] = bl0[3];
        b0[4] = bh0[0]; b0[5] = bh0[1]; b0[6] = bh0[2]; b0[7] = bh0[3];
        b1[0] = bl1[0]; b1[1] = bl1[1]; b1[2] = bl1[2]; b1[3] = bl1[3];
        b1[4] = bh1[0]; b1[5] = bh1[1]; b1[6] = bh1[2]; b1[7] = bh1[3];
        acc[0][0] = __builtin_amdgcn_mfma_f32_16x16x32_bf16(a0, b0, acc[0][0], 0, 0, 0);
        acc[0][1] = __builtin_amdgcn_mfma_f32_16x16x32_bf16(a0, b1, acc[0][1], 0, 0, 0);
        acc[1][0] = __builtin_amdgcn_mfma_f32_16x16x32_bf16(a1, b0, acc[1][0], 0, 0, 0);
        acc[1][1] = __builtin_amdgcn_mfma_f32_16x16x32_bf16(a1, b1, acc[1][1], 0, 0, 0);
        acc[2][0] = __builtin_amdgcn_mfma_f32_16x16x32_bf16(a2, b0, acc[2][0], 0, 0, 0);
        acc[2][1] = __builtin_amdgcn_mfma_f32_16x16x32_bf16(a2, b1, acc[2][1], 0, 0, 0);
        acc[3][0] = __builtin_amdgcn_mfma_f32_16x16x32_bf16(a3, b0, acc[3][0], 0, 0, 0);
        acc[3][1] = __builtin_amdgcn_mfma_f32_16x16x32_bf16(a3, b1, acc[3][1], 0, 0, 0);
        if (t < 7) CONV_WRITE((t + 1) & 1);
        __syncthreads();
    }
#undef CONV_LOAD
#undef CONV_WRITE
#undef W4

    #pragma unroll
    for (int ni = 0; ni < 2; ++ni) {
        int o = o0 + wn * 32 + ni * 16 + fr;
        float cb = conv_b[o];
        int obase = (o >> 5) * 8192 + (((o >> 3) & 3)) * 128 + (o & 7);
        #pragma unroll
        for (int mi = 0; mi < 4; ++mi)
            #pragma unroll
            for (int i = 0; i < 4; ++i) {
                int gm = m0 + wm * 64 + mi * 16 + fg * 4 + i;
                int n = gm / 49, hw = gm - n * 49;
                xb[(size_t)hw * 65536 + obase + (n >> 4) * 512 + (n & 15) * 8]
                    = f2bf(acc[mi][ni][i] + cb);
            }
    }
}

// ---------------- FC1: bf16 MFMA; A fragments loaded DIRECTLY from global (xb is
// fragment-linear), B = w1 via 4-deep reg ring -> LDS dbuf + tr-read. 1 barrier/step. ----
__global__ __launch_bounds__(512) void fc1_mfma(const ushort* __restrict__ xb,
                                                const float* __restrict__ w1,
                                                ushort* __restrict__ partb) {
    __shared__ __align__(16) ushort Bbf[2][2048];
    const int s = blockIdx.x, nblk = blockIdx.y;   // grid (8,32): same-s blocks share an XCD
    const int n0 = nblk * 64;
    const int k0 = s * 1568;
    const int tid = threadIdx.x;
    const int lane = tid & 63, w = tid >> 6;
    const int wm = w & 3, wn = w >> 2;
    const int fr = lane & 15, fg = lane >> 4;

    const ushort* gA = xb + (size_t)s * 49 * 8192;

    const int kr = (w >> 2) * 16 + (lane >> 2);
    const int bnb = w & 3, bnq = lane & 3;
    const int ncol = n0 + bnb * 16 + bnq * 4;
    const int bw_u = bnb * 512 + kr * 16 + bnq * 4;

    const int aoff = wm * 2048 + fg * 128 + fr * 8;
    f4v acc[4][2];
    #pragma unroll
    for (int i = 0; i < 4; ++i)
        #pragma unroll
        for (int j = 0; j < 2; ++j) acc[i][j] = (f4v){0.f, 0.f, 0.f, 0.f};

// k' -> orig w1 row: kk = k0 + t*32 + kr; row = (kk&255)*49 + (kk>>8)
#define GBP(t) (*(const float4*)(w1 +                                                           \
    (size_t)(((unsigned)(k0 + (t) * 32 + kr) & 255u) * 49 +                                     \
             ((unsigned)(k0 + (t) * 32 + kr) >> 8)) * 2048 + ncol))
#define BWRITE(buf, rb) do {                                                                    \
    s4v _u; _u[0] = (short)f2bf((rb).x); _u[1] = (short)f2bf((rb).y);                           \
    _u[2] = (short)f2bf((rb).z); _u[3] = (short)f2bf((rb).w);                                   \
    *(s4v*)&Bbf[buf][bw_u] = _u;                                                                \
} while (0)

    s8v aA0, aA1, aA2, aA3, aB0, aB1, aB2, aB3;
    float4 rb0, rb1, rb2, rb3;

    // prologue: A(0) into aA, B ring 4-deep, B(0) into LDS
    {
        const ushort* _g0 = gA;
        aA0 = *(const s8v*)(_g0 + aoff);
        aA1 = *(const s8v*)(_g0 + aoff + 512);
        aA2 = *(const s8v*)(_g0 + aoff + 1024);
        aA3 = *(const s8v*)(_g0 + aoff + 1536);
    }
    rb0 = GBP(0); rb1 = GBP(1); rb2 = GBP(2); rb3 = GBP(3);
    BWRITE(0, rb0);
    __syncthreads();

#define FC1_BODY(t, rbL, rbU, aC0, aC1, aC2, aC3, aN0, aN1, aN2, aN3) do {                      \
    int kg1 = (t) + 1 > 48 ? 48 : (t) + 1;                                                      \
    int kg4 = (t) + 4 > 48 ? 48 : (t) + 4;                                                      \
    const ushort* _gn = gA + (size_t)kg1 * 8192;                                                \
    aN0 = *(const s8v*)(_gn + aoff);                                                            \
    aN1 = *(const s8v*)(_gn + aoff + 512);                                                      \
    aN2 = *(const s8v*)(_gn + aoff + 1024);                                                     \
    aN3 = *(const s8v*)(_gn + aoff + 1536);                                                     \
    rbL = GBP(kg4);                                                                             \
    unsigned _bb = (unsigned)(size_t)(&Bbf[(t) & 1][0]) + wn * 2048 + fg * 256 + fr * 2;        \
    s4v _bl0, _bh0, _bl1, _bh1;                                                                 \
    asm volatile("ds_read_b64_tr_b16 %0, %2\n\t"                                                \
                 "ds_read_b64_tr_b16 %1, %2 offset:128"                                         \
                 : "=v"(_bl0), "=v"(_bh0) : "v"(_bb));                                          \
    asm volatile("ds_read_b64_tr_b16 %0, %2 offset:1024\n\t"                                    \
                 "ds_read_b64_tr_b16 %1, %2 offset:1152"                                        \
                 : "=v"(_bl1), "=v"(_bh1) : "v"(_bb));                                          \
    asm volatile("s_waitcnt lgkmcnt(0)" ::: "memory");                                          \
    __builtin_amdgcn_sched_barrier(0);                                                          \
    s8v _b0, _b1;                                                                               \
    _b0[0]=_bl0[0]; _b0[1]=_bl0[1]; _b0[2]=_bl0[2]; _b0[3]=_bl0[3];                             \
    _b0[4]=_bh0[0]; _b0[5]=_bh0[1]; _b0[6]=_bh0[2]; _b0[7]=_bh0[3];                             \
    _b1[0]=_bl1[0]; _b1[1]=_bl1[1]; _b1[2]=_bl1[2]; _b1[3]=_bl1[3];                             \
    _b1[4]=_bh1[0]; _b1[5]=_bh1[1]; _b1[6]=_bh1[2]; _b1[7]=_bh1[3];                             \
    acc[0][0] = __builtin_amdgcn_mfma_f32_16x16x32_bf16(aC0, _b0, acc[0][0], 0, 0, 0);          \
    acc[0][1] = __builtin_amdgcn_mfma_f32_16x16x32_bf16(aC0, _b1, acc[0][1], 0, 0, 0);          \
    acc[1][0] = __builtin_amdgcn_mfma_f32_16x16x32_bf16(aC1, _b0, acc[1][0], 0, 0, 0);          \
    acc[1][1] = __builtin_amdgcn_mfma_f32_16x16x32_bf16(aC1, _b1, acc[1][1], 0, 0, 0);          \
    acc[2][0] = __builtin_amdgcn_mfma_f32_16x16x32_bf16(aC2, _b0, acc[2][0], 0, 0, 0);          \
    acc[2][1] = __builtin_amdgcn_mfma_f32_16x16x32_bf16(aC2, _b1, acc[2][1], 0, 0, 0);          \
    acc[3][0] = __builtin_amdgcn_mfma_f32_16x16x32_bf16(aC3, _b0, acc[3][0], 0, 0, 0);          \
    acc[3][1] = __builtin_amdgcn_mfma_f32_16x16x32_bf16(aC3, _b1, acc[3][1], 0, 0, 0);          \
    BWRITE(((t) + 1) & 1, rbU);                                                                 \
    __syncthreads();                                                                            \
} while (0)

    for (int tb = 0; tb < 48; tb += 4) {
        FC1_BODY(tb + 0, rb0, rb1, aA0, aA1, aA2, aA3, aB0, aB1, aB2, aB3);
        FC1_BODY(tb + 1, rb1, rb2, aB0, aB1, aB2, aB3, aA0, aA1, aA2, aA3);
        FC1_BODY(tb + 2, rb2, rb3, aA0, aA1, aA2, aA3, aB0, aB1, aB2, aB3);
        FC1_BODY(tb + 3, rb3, rb0, aB0, aB1, aB2, aB3, aA0, aA1, aA2, aA3);
    }

    // final step t=48 (even -> current frags in aA), Bbf[0]
    {
        unsigned _bb = (unsigned)(size_t)(&Bbf[0][0]) + wn * 2048 + fg * 256 + fr * 2;
        s4v _bl0, _bh0, _bl1, _bh1;
        asm volatile("ds_read_b64_tr_b16 %0, %2\n\t"
                     "ds_read_b64_tr_b16 %1, %2 offset:128"
                     : "=v"(_bl0), "=v"(_bh0) : "v"(_bb));
        asm volatile("ds_read_b64_tr_b16 %0, %2 offset:1024\n\t"
                     "ds_read_b64_tr_b16 %1, %2 offset:1152"
                     : "=v"(_bl1), "=v"(_bh1) : "v"(_bb));
        asm volatile("s_waitcnt lgkmcnt(0)" ::: "memory");
        __builtin_amdgcn_sched_barrier(0);
        s8v _b0, _b1;
        _b0[0]=_bl0[0]; _b0[1]=_bl0[1]; _b0[2]=_bl0[2]; _b0[3]=_bl0[3];
        _b0[4]=_bh0[0]; _b0[5]=_bh0[1]; _b0[6]=_bh0[2]; _b0[7]=_bh0[3];
        _b1[0]=_bl1[0]; _b1[1]=_bl1[1]; _b1[2]=_bl1[2]; _b1[3]=_bl1[3];
        _b1[4]=_bh1[0]; _b1[5]=_bh1[1]; _b1[6]=_bh1[2]; _b1[7]=_bh1[3];
        acc[0][0] = __builtin_amdgcn_mfma_f32_16x16x32_bf16(aA0, _b0, acc[0][0], 0, 0, 0);
        acc[0][1] = __builtin_amdgcn_mfma_f32_16x16x32_bf16(aA0, _b1, acc[0][1], 0, 0, 0);
        acc[1][0] = __builtin_amdgcn_mfma_f32_16x16x32_bf16(aA1, _b0, acc[1][0], 0, 0, 0);
        acc[1][1] = __builtin_amdgcn_mfma_f32_16x16x32_bf16(aA1, _b1, acc[1][1], 0, 0, 0);
        acc[2][0] = __builtin_amdgcn_mfma_f32_16x16x32_bf16(aA2, _b0, acc[2][0], 0, 0, 0);
        acc[2][1] = __builtin_amdgcn_mfma_f32_16x16x32_bf16(aA2, _b1, acc[2][1], 0, 0, 0);
        acc[3][0] = __builtin_amdgcn_mfma_f32_16x16x32_bf16(aA3, _b0, acc[3][0], 0, 0, 0);
        acc[3][1] = __builtin_amdgcn_mfma_f32_16x16x32_bf16(aA3, _b1, acc[3][1], 0, 0, 0);
    }
#undef FC1_BODY
#undef GBP
#undef BWRITE

    // epilogue: bf16 partial write
    ushort* dst = partb + (size_t)s * 524288 + n0 + wn * 32 + fr;
    #pragma unroll
    for (int mi = 0; mi < 4; ++mi)
        #pragma unroll
        for (int ni = 0; ni < 2; ++ni)
            #pragma unroll
            for (int i = 0; i < 4; ++i) {
                int row = wm * 64 + mi * 16 + fg * 4 + i;
                dst[(size_t)row * 2048 + ni * 16] = f2bf(acc[mi][ni][i]);
            }
}

// ---------------- fc3 fused: bbox[m][n] = relu-free (h2 @ wp + bp) ----------------
__global__ __launch_bounds__(256) void fc3_small(const float* __restrict__ h2,
                                                 const float* __restrict__ wp,
                                                 const float* __restrict__ bp,
                                                 float* __restrict__ bbox) {
    __shared__ float sh2[8][512];
    int blk = blockIdx.x;           // 32 blocks, 8 rows each
    int tid = threadIdx.x;
    int n = tid & 63;
    int mr = tid >> 6;              // 0..3 -> rows mr, mr+4
    int m0 = blk * 8;
    for (int i = tid; i < 8 * 512; i += 256)
        sh2[i >> 9][i & 511] = h2[(size_t)(m0 + (i >> 9)) * 512 + (i & 511)];
    __syncthreads();
    float b = bp[n];
    float acc0 = b, acc1 = b;
    for (int k = 0; k < 512; ++k) {
        float wv = wp[k * 64 + n];
        acc0 += sh2[mr][k] * wv;
        acc1 += sh2[mr + 4][k] * wv;
    }
    bbox[(size_t)(m0 + mr) * 64 + n] = acc0;
    bbox[(size_t)(m0 + mr + 4) * 64 + n] = acc1;
}

extern "C" void kernel_launch(void* const* d_in, const int* in_sizes, int n_in,
                              void* d_out, int out_size, void* d_ws, size_t ws_size,
                              hipStream_t stream) {
    const float* base   = (const float*)d_in[0];
    const float* tubes  = (const float*)d_in[1];
    const float* conv_w = (const float*)d_in[4];
    const float* conv_b = (const float*)d_in[5];
    const float* w1     = (const float*)d_in[6];
    const float* b1     = (const float*)d_in[7];
    const float* w2     = (const float*)d_in[8];
    const float* b2     = (const float*)d_in[9];
    const float* wp     = (const float*)d_in[10];
    const float* bp     = (const float*)d_in[11];

    float* out    = (float*)d_out;
    float* bbox   = out;
    float* pooled = out + 16384;
    float* rois   = out + 16384 + 3211264;

    float* ws      = (float*)d_ws;
    float* inv     = ws;                         // 12544
    float* partial = ws + 12544;                 // 100352
    float* tsum    = ws + 112896;                // 200704
    float* pooledT = ws + 313600;                // 3211264
    ushort* xb     = (ushort*)(ws + 3524864);    // 6.4MB region
    float* h1      = ws + 6736128;               // 524288
    float* h2      = ws + 7260416;               // 131072
    float* part    = ws + 7391488;               // fp32 part (fc2)
    ushort* partb  = (ushort*)part;              // bf16 part (fc1): 4.2M ushorts

    k_sumsq<<<BB * TT * 8, 256, 0, stream>>>(base, partial);
    k_finish_inv<<<49, 256, 0, stream>>>(partial, inv);
    k_tsum<<<BB * CC, 256, 0, stream>>>(base, inv, tsum);
    k_roialign<<<NROI, 256, 0, stream>>>(tubes, tsum, pooled, pooledT, rois);

    // conv 1x1 via MFMA, writes xb (bf16 fragment-linear, k'-permuted) directly
    conv_mfma<<<dim3(49, 4), 512, 0, stream>>>(pooledT, conv_w, conv_b, xb);

    // fc1: (256 x 12544) @ (12544 x 2048), bf16 MFMA, split-K 8, direct-fragment A loads
    fc1_mfma<<<dim3(8, 32), 512, 0, stream>>>(xb, w1, partb);
    k_reduce_bf<<<2048, 256, 0, stream>>>(partb, b1, h1);

    // fc2: (256 x 2048) @ (2048 x 512), fp32, split-K 8
    gemm64<<<dim3(4, 8, 8), 256, 0, stream>>>(h1, w2, part,
                                              256, 512, 2048, 2048, 512, 256);
    k_reduce<<<(256 * 512 + 255) / 256, 256, 0, stream>>>(part, b2, h2, 256 * 512, 512, 8, 1);

    // fc3: fused single kernel
    fc3_small<<<32, 256, 0, stream>>>(h2, wp, bp, bbox);
}

// Round 7
// 123.054 us; speedup vs baseline: 1.0575x; 1.0575x over previous
//
#include <hip/hip_runtime.h>

#define HH 14
#define WW 14
#define HWSZ 196
#define TT 16
#define CC 256
#define BB 4
#define RR 64
#define NROI 256
#define PP 7
#define PP2 49

typedef short s4v __attribute__((ext_vector_type(4)));
typedef short s8v __attribute__((ext_vector_type(8)));
typedef float f4v __attribute__((ext_vector_type(4)));

__device__ inline ushort f2bf(float f) {
    union { float f; unsigned u; } v; v.f = f;
    unsigned r = v.u + 0x7fffu + ((v.u >> 16) & 1u);
    return (ushort)(r >> 16);
}
__device__ inline float bf2f(ushort u) {
    union { unsigned u; float f; } v; v.u = ((unsigned)u) << 16;
    return v.f;
}

// ---------------- sumsq partials ----------------
__global__ void k_sumsq(const float* __restrict__ base, float* __restrict__ partial) {
    int blk = blockIdx.x;            // bt*8 + cg
    int bt = blk >> 3, cg = blk & 7;
    int hw = threadIdx.x;
    if (hw >= HWSZ) return;
    int b = bt >> 4, t = bt & 15;
    const float* p = base + ((size_t)(b * CC + cg * 32) * TT + t) * HWSZ + hw;
    float s = 0.f;
    #pragma unroll 8
    for (int c = 0; c < 32; ++c) {
        float v = p[(size_t)c * TT * HWSZ];
        s += v * v;
    }
    partial[cg * 12544 + bt * HWSZ + hw] = s;
}

// ---------------- finish: inv = 1/max(sqrt(sum),1e-12) ----------------
__global__ void k_finish_inv(const float* __restrict__ partial, float* __restrict__ inv) {
    int j = blockIdx.x * 256 + threadIdx.x;
    if (j >= 12544) return;
    float s = 0.f;
    #pragma unroll
    for (int cg = 0; cg < 8; ++cg) s += partial[cg * 12544 + j];
    inv[j] = 1.0f / fmaxf(sqrtf(s), 1e-12f);
}

// ---------------- tsum ----------------
__global__ void k_tsum(const float* __restrict__ base, const float* __restrict__ inv,
                       float* __restrict__ tsum) {
    int bc = blockIdx.x;
    int hw = threadIdx.x;
    if (hw >= HWSZ) return;
    int b = bc >> 8;
    const float* p = base + (size_t)bc * TT * HWSZ + hw;
    const float* iv = inv + b * TT * HWSZ + hw;
    float s = 0.f;
    #pragma unroll
    for (int t = 0; t < TT; ++t) s += p[t * HWSZ] * iv[t * HWSZ];
    tsum[(size_t)bc * HWSZ + hw] = s;
}

// ---------------- ROI align (+rois fused); both outputs coalesced ----------------
__global__ void k_roialign(const float* __restrict__ tubes, const float* __restrict__ tsum,
                           float* __restrict__ pooled, float* __restrict__ pooledT,
                           float* __restrict__ rois) {
    __shared__ int sx0[PP], sx1[PP], sy0[PP], sy1[PP];
    __shared__ float sfx[PP], sfy[PP];
    __shared__ int sb;
    int n = blockIdx.x;
    int tid = threadIdx.x;
    if (tid < PP) {
        const float* tb = tubes + n * 7;
        float x1 = tb[1] * 0.0625f, y1 = tb[2] * 0.0625f;
        float x2 = tb[4] * 0.0625f, y2 = tb[5] * 0.0625f;
        float bw = fmaxf(x2 - x1 + 0.0625f, 0.001f) * (1.0f / PP);
        float bh = fmaxf(y2 - y1 + 0.0625f, 0.001f) * (1.0f / PP);
        float ctr = tid + 0.5f;
        float xs = fminf(fmaxf(x1 + ctr * bw, 0.f), (float)(WW - 1));
        float ys = fminf(fmaxf(y1 + ctr * bh, 0.f), (float)(HH - 1));
        float x0f = floorf(xs), y0f = floorf(ys);
        int x0 = (int)x0f, y0 = (int)y0f;
        sx0[tid] = x0; sx1[tid] = min(x0 + 1, WW - 1);
        sy0[tid] = y0; sy1[tid] = min(y0 + 1, HH - 1);
        sfx[tid] = xs - x0f; sfy[tid] = ys - y0f;
        if (tid == 0) sb = (int)tb[0];
    }
    if (tid < TT) {
        const float* tb = tubes + n * 7;
        int t1 = (int)tb[3], t2 = (int)tb[6];
        bool m = (tid >= t1) && (tid <= t2);
        int b = n >> 6;
        float* o = rois + ((size_t)n * TT + tid) * 5;
        o[0] = (float)(b * TT + tid);
        o[1] = m ? tb[1] : 0.f;
        o[2] = m ? tb[2] : 0.f;
        o[3] = m ? tb[4] : 0.f;
        o[4] = m ? tb[5] : 0.f;
    }
    __syncthreads();
    const float* tbase = tsum + (size_t)sb * CC * HWSZ;

    for (int idx = tid; idx < CC * PP2; idx += 256) {
        int c = idx / PP2, bin = idx - (idx / PP2) * PP2;
        int py = bin / PP, px = bin - (bin / PP) * PP;
        const float* tp = tbase + (size_t)c * HWSZ;
        float fx = sfx[px], fy = sfy[py];
        int y0 = sy0[py] * WW, y1 = sy1[py] * WW;
        float v00 = tp[y0 + sx0[px]];
        float v01 = tp[y0 + sx1[px]];
        float v10 = tp[y1 + sx0[px]];
        float v11 = tp[y1 + sx1[px]];
        float v = (1.f - fy) * ((1.f - fx) * v00 + fx * v01)
                + fy        * ((1.f - fx) * v10 + fx * v11);
        pooled[(size_t)n * CC * PP2 + idx] = v * (1.0f / TT);
    }
    for (int idx = tid; idx < PP2 * CC; idx += 256) {
        int bin = idx >> 8, c = idx & 255;
        int py = bin / PP, px = bin - (bin / PP) * PP;
        const float* tp = tbase + (size_t)c * HWSZ;
        float fx = sfx[px], fy = sfy[py];
        int y0 = sy0[py] * WW, y1 = sy1[py] * WW;
        float v00 = tp[y0 + sx0[px]];
        float v01 = tp[y0 + sx1[px]];
        float v10 = tp[y1 + sx0[px]];
        float v11 = tp[y1 + sx1[px]];
        float v = (1.f - fy) * ((1.f - fx) * v00 + fx * v01)
                + fy        * ((1.f - fx) * v10 + fx * v11);
        pooledT[((size_t)n * PP2 + bin) * CC + c] = v * (1.0f / TT);
    }
}

// ---------------- conv 1x1 via MFMA; epilogue writes xb (bf16, k'-permuted fragment layout) ----
__global__ __launch_bounds__(512) void conv_mfma(const float* __restrict__ pooledT,
                                                 const float* __restrict__ conv_w,
                                                 const float* __restrict__ conv_b,
                                                 ushort* __restrict__ xb) {
    __shared__ __align__(16) ushort Ab[2][8192];
    __shared__ __align__(16) ushort Bres[8192];
    const int m0 = blockIdx.x * 256, o0 = blockIdx.y * 64;
    const int tid = threadIdx.x;
    const int lane = tid & 63, w = tid >> 6;
    const int wm = w & 3, wn = w >> 2;
    const int fr = lane & 15, fg = lane >> 4;

    for (int ii = tid; ii < 2048; ii += 512) {
        int o_l = ii >> 5, cq = ii & 31;
        const float* s = conv_w + (size_t)(o0 + o_l) * 256 + cq * 8;
        float4 v0 = *(const float4*)s;
        float4 v1 = *(const float4*)(s + 4);
        float vv[8] = {v0.x, v0.y, v0.z, v0.w, v1.x, v1.y, v1.z, v1.w};
        int dbase = (cq >> 2) * 2048 + (o_l >> 4) * 512 + (cq & 3) * 128 + (o_l & 15);
        #pragma unroll
        for (int jc = 0; jc < 8; ++jc) Bres[dbase + jc * 16] = f2bf(vv[jc]);
    }

    int ii0 = tid, ii1 = 512 + tid, ii2 = 1024 + tid, ii3 = 1536 + tid;
    const float* pA0 = pooledT + (size_t)(m0 + (ii0 >> 3)) * 256 + (ii0 & 7) * 4;
    const float* pA1 = pooledT + (size_t)(m0 + (ii1 >> 3)) * 256 + (ii1 & 7) * 4;
    const float* pA2 = pooledT + (size_t)(m0 + (ii2 >> 3)) * 256 + (ii2 & 7) * 4;
    const float* pA3 = pooledT + (size_t)(m0 + (ii3 >> 3)) * 256 + (ii3 & 7) * 4;
#define CDOFF(ii) (((ii >> 3) >> 4) * 512 + ((ii & 7) >> 1) * 128 + ((ii >> 3) & 15) * 8 + (ii & 1) * 4)
    const int do0 = CDOFF(ii0), do1 = CDOFF(ii1), do2 = CDOFF(ii2), do3 = CDOFF(ii3);
#undef CDOFF
    float4 a0_, a1_, a2_, a3_;
#define CONV_LOAD(t) do { a0_ = *(const float4*)(pA0 + (t) * 32); \
                          a1_ = *(const float4*)(pA1 + (t) * 32); \
                          a2_ = *(const float4*)(pA2 + (t) * 32); \
                          a3_ = *(const float4*)(pA3 + (t) * 32); } while (0)
#define W4(dst, v) do { s4v _u; _u[0]=(short)f2bf((v).x); _u[1]=(short)f2bf((v).y); \
                        _u[2]=(short)f2bf((v).z); _u[3]=(short)f2bf((v).w); \
                        *(s4v*)(dst) = _u; } while (0)
#define CONV_WRITE(buf) do { W4(Ab[buf] + do0, a0_); W4(Ab[buf] + do1, a1_); \
                             W4(Ab[buf] + do2, a2_); W4(Ab[buf] + do3, a3_); } while (0)

    CONV_LOAD(0);
    CONV_WRITE(0);
    __syncthreads();

    const int aoff = wm * 2048 + fg * 128 + fr * 8;
    f4v acc[4][2];
    #pragma unroll
    for (int i = 0; i < 4; ++i)
        #pragma unroll
        for (int j = 0; j < 2; ++j) acc[i][j] = (f4v){0.f, 0.f, 0.f, 0.f};

    for (int t = 0; t < 8; ++t) {
        if (t < 7) CONV_LOAD(t + 1);
        const ushort* A = Ab[t & 1];
        s8v a0 = *(const s8v*)(A + aoff);
        s8v a1 = *(const s8v*)(A + aoff + 512);
        s8v a2 = *(const s8v*)(A + aoff + 1024);
        s8v a3 = *(const s8v*)(A + aoff + 1536);
        unsigned bbase = (unsigned)(size_t)(&Bres[0]) + t * 4096 + wn * 2048 + fg * 256 + fr * 2;
        s4v bl0, bh0, bl1, bh1;
        asm volatile("ds_read_b64_tr_b16 %0, %2\n\t"
                     "ds_read_b64_tr_b16 %1, %2 offset:128"
                     : "=v"(bl0), "=v"(bh0) : "v"(bbase));
        asm volatile("ds_read_b64_tr_b16 %0, %2 offset:1024\n\t"
                     "ds_read_b64_tr_b16 %1, %2 offset:1152"
                     : "=v"(bl1), "=v"(bh1) : "v"(bbase));
        asm volatile("s_waitcnt lgkmcnt(0)" ::: "memory");
        __builtin_amdgcn_sched_barrier(0);
        s8v b0, b1;
        b0[0] = bl0[0]; b0[1] = bl0[1]; b0[2] = bl0[2]; b0[3] = bl0[3];
        b0[4] = bh0[0]; b0[5] = bh0[1]; b0[6] = bh0[2]; b0[7] = bh0[3];
        b1[0] = bl1[0]; b1[1] = bl1[1]; b1[2] = bl1[2]; b1[3] = bl1[3];
        b1[4] = bh1[0]; b1[5] = bh1[1]; b1[6] = bh1[2]; b1[7] = bh1[3];
        acc[0][0] = __builtin_amdgcn_mfma_f32_16x16x32_bf16(a0, b0, acc[0][0], 0, 0, 0);
        acc[0][1] = __builtin_amdgcn_mfma_f32_16x16x32_bf16(a0, b1, acc[0][1], 0, 0, 0);
        acc[1][0] = __builtin_amdgcn_mfma_f32_16x16x32_bf16(a1, b0, acc[1][0], 0, 0, 0);
        acc[1][1] = __builtin_amdgcn_mfma_f32_16x16x32_bf16(a1, b1, acc[1][1], 0, 0, 0);
        acc[2][0] = __builtin_amdgcn_mfma_f32_16x16x32_bf16(a2, b0, acc[2][0], 0, 0, 0);
        acc[2][1] = __builtin_amdgcn_mfma_f32_16x16x32_bf16(a2, b1, acc[2][1], 0, 0, 0);
        acc[3][0] = __builtin_amdgcn_mfma_f32_16x16x32_bf16(a3, b0, acc[3][0], 0, 0, 0);
        acc[3][1] = __builtin_amdgcn_mfma_f32_16x16x32_bf16(a3, b1, acc[3][1], 0, 0, 0);
        if (t < 7) CONV_WRITE((t + 1) & 1);
        __syncthreads();
    }
#undef CONV_LOAD
#undef CONV_WRITE
#undef W4

    #pragma unroll
    for (int ni = 0; ni < 2; ++ni) {
        int o = o0 + wn * 32 + ni * 16 + fr;
        float cb = conv_b[o];
        int obase = (o >> 5) * 8192 + (((o >> 3) & 3)) * 128 + (o & 7);
        #pragma unroll
        for (int mi = 0; mi < 4; ++mi)
            #pragma unroll
            for (int i = 0; i < 4; ++i) {
                int gm = m0 + wm * 64 + mi * 16 + fg * 4 + i;
                int n = gm / 49, hw = gm - n * 49;
                xb[(size_t)hw * 65536 + obase + (n >> 4) * 512 + (n & 15) * 8]
                    = f2bf(acc[mi][ni][i] + cb);
            }
    }
}

// ---------------- FC1: bf16 MFMA, deep pipeline (A: gload_lds depth2, B: reg ring depth4) ----
__global__ __launch_bounds__(512) void fc1_mfma(const ushort* __restrict__ xb,
                                                const float* __restrict__ w1,
                                                ushort* __restrict__ partb) {
    __shared__ __align__(16) ushort Ab[4][8192];
    __shared__ __align__(16) ushort Bbf[2][2048];
    const int s = blockIdx.x, nblk = blockIdx.y;   // grid (8,32): same-s blocks share an XCD
    const int n0 = nblk * 64;
    const int k0 = s * 1568;
    const int tid = threadIdx.x;
    const int lane = tid & 63, w = tid >> 6;
    const int wm = w & 3, wn = w >> 2;
    const int fr = lane & 15, fg = lane >> 4;

    const ushort* gA = xb + (size_t)s * 49 * 8192;
    const int slot0 = tid, slot1 = 512 + tid;

    const int kr = (w >> 2) * 16 + (lane >> 2);
    const int bnb = w & 3, bnq = lane & 3;
    const int ncol = n0 + bnb * 16 + bnq * 4;
    const int bw_u = bnb * 512 + kr * 16 + bnq * 4;

    const int aoff = wm * 2048 + fg * 128 + fr * 8;
    f4v acc[4][2];
    #pragma unroll
    for (int i = 0; i < 4; ++i)
        #pragma unroll
        for (int j = 0; j < 2; ++j) acc[i][j] = (f4v){0.f, 0.f, 0.f, 0.f};

#define STAGE_A(buf, kg) do {                                                                   \
    ushort* _d = Ab[buf];                                                                       \
    __builtin_amdgcn_global_load_lds(                                                           \
        (const __attribute__((address_space(1))) void*)(gA + (size_t)(kg) * 8192 + slot0 * 8),  \
        (__attribute__((address_space(3))) void*)(_d + slot0 * 8), 16, 0, 0);                   \
    __builtin_amdgcn_global_load_lds(                                                           \
        (const __attribute__((address_space(1))) void*)(gA + (size_t)(kg) * 8192 + slot1 * 8),  \
        (__attribute__((address_space(3))) void*)(_d + slot1 * 8), 16, 0, 0);                   \
} while (0)
// k' -> orig w1 row: kk = k0 + t*32 + kr; row = (kk&255)*49 + (kk>>8)
#define GBP(t) (*(const float4*)(w1 +                                                           \
    (size_t)(((unsigned)(k0 + (t) * 32 + kr) & 255u) * 49 +                                     \
             ((unsigned)(k0 + (t) * 32 + kr) >> 8)) * 2048 + ncol))
#define BWRITE(buf, rb) do {                                                                    \
    s4v _u; _u[0] = (short)f2bf((rb).x); _u[1] = (short)f2bf((rb).y);                           \
    _u[2] = (short)f2bf((rb).z); _u[3] = (short)f2bf((rb).w);                                   \
    *(s4v*)&Bbf[buf][bw_u] = _u;                                                                \
} while (0)

    float4 rb0, rb1, rb2, rb3;
    STAGE_A(0, 0);
    STAGE_A(1, 1);
    rb0 = GBP(0); rb1 = GBP(1); rb2 = GBP(2); rb3 = GBP(3);
    BWRITE(0, rb0);
    __builtin_amdgcn_sched_barrier(0);
    asm volatile("s_waitcnt vmcnt(3) lgkmcnt(0)" ::: "memory");
    __builtin_amdgcn_s_barrier();
    __builtin_amdgcn_sched_barrier(0);

#define FC1_BODY(t, rbL, rbU) do {                                                              \
    int kg2 = (t) + 2 > 48 ? 48 : (t) + 2;                                                      \
    int kg4 = (t) + 4 > 48 ? 48 : (t) + 4;                                                      \
    STAGE_A(((t) + 2) & 3, kg2);                                                                \
    __builtin_amdgcn_sched_barrier(0);                                                          \
    rbL = GBP(kg4);                                                                             \
    __builtin_amdgcn_sched_barrier(0);                                                          \
    const ushort* _A = Ab[(t) & 3];                                                             \
    s8v _a0 = *(const s8v*)(_A + aoff);                                                         \
    s8v _a1 = *(const s8v*)(_A + aoff + 512);                                                   \
    s8v _a2 = *(const s8v*)(_A + aoff + 1024);                                                  \
    s8v _a3 = *(const s8v*)(_A + aoff + 1536);                                                  \
    unsigned _bb = (unsigned)(size_t)(&Bbf[(t) & 1][0]) + wn * 2048 + fg * 256 + fr * 2;        \
    s4v _bl0, _bh0, _bl1, _bh1;                                                                 \
    asm volatile("ds_read_b64_tr_b16 %0, %2\n\t"                                                \
                 "ds_read_b64_tr_b16 %1, %2 offset:128"                                         \
                 : "=v"(_bl0), "=v"(_bh0) : "v"(_bb));                                          \
    asm volatile("ds_read_b64_tr_b16 %0, %2 offset:1024\n\t"                                    \
                 "ds_read_b64_tr_b16 %1, %2 offset:1152"                                        \
                 : "=v"(_bl1), "=v"(_bh1) : "v"(_bb));                                          \
    asm volatile("s_waitcnt lgkmcnt(0)" ::: "memory");                                          \
    __builtin_amdgcn_sched_barrier(0);                                                          \
    s8v _b0, _b1;                                                                               \
    _b0[0]=_bl0[0]; _b0[1]=_bl0[1]; _b0[2]=_bl0[2]; _b0[3]=_bl0[3];                             \
    _b0[4]=_bh0[0]; _b0[5]=_bh0[1]; _b0[6]=_bh0[2]; _b0[7]=_bh0[3];                             \
    _b1[0]=_bl1[0]; _b1[1]=_bl1[1]; _b1[2]=_bl1[2]; _b1[3]=_bl1[3];                             \
    _b1[4]=_bh1[0]; _b1[5]=_bh1[1]; _b1[6]=_bh1[2]; _b1[7]=_bh1[3];                             \
    acc[0][0] = __builtin_amdgcn_mfma_f32_16x16x32_bf16(_a0, _b0, acc[0][0], 0, 0, 0);          \
    acc[0][1] = __builtin_amdgcn_mfma_f32_16x16x32_bf16(_a0, _b1, acc[0][1], 0, 0, 0);          \
    acc[1][0] = __builtin_amdgcn_mfma_f32_16x16x32_bf16(_a1, _b0, acc[1][0], 0, 0, 0);          \
    acc[1][1] = __builtin_amdgcn_mfma_f32_16x16x32_bf16(_a1, _b1, acc[1][1], 0, 0, 0);          \
    acc[2][0] = __builtin_amdgcn_mfma_f32_16x16x32_bf16(_a2, _b0, acc[2][0], 0, 0, 0);          \
    acc[2][1] = __builtin_amdgcn_mfma_f32_16x16x32_bf16(_a2, _b1, acc[2][1], 0, 0, 0);          \
    acc[3][0] = __builtin_amdgcn_mfma_f32_16x16x32_bf16(_a3, _b0, acc[3][0], 0, 0, 0);          \
    acc[3][1] = __builtin_amdgcn_mfma_f32_16x16x32_bf16(_a3, _b1, acc[3][1], 0, 0, 0);          \
    BWRITE(((t) + 1) & 1, rbU);                                                                 \
    __builtin_amdgcn_sched_barrier(0);                                                          \
    asm volatile("s_waitcnt vmcnt(4) lgkmcnt(0)" ::: "memory");                                 \
    __builtin_amdgcn_s_barrier();                                                               \
    __builtin_amdgcn_sched_barrier(0);                                                          \
} while (0)

    for (int tb = 0; tb < 48; tb += 4) {
        FC1_BODY(tb + 0, rb0, rb1);
        FC1_BODY(tb + 1, rb1, rb2);
        FC1_BODY(tb + 2, rb2, rb3);
        FC1_BODY(tb + 3, rb3, rb0);
    }

    // final step t=48: compute only (Ab[0], Bbf[0])
    {
        const ushort* _A = Ab[0];
        s8v _a0 = *(const s8v*)(_A + aoff);
        s8v _a1 = *(const s8v*)(_A + aoff + 512);
        s8v _a2 = *(const s8v*)(_A + aoff + 1024);
        s8v _a3 = *(const s8v*)(_A + aoff + 1536);
        unsigned _bb = (unsigned)(size_t)(&Bbf[0][0]) + wn * 2048 + fg * 256 + fr * 2;
        s4v _bl0, _bh0, _bl1, _bh1;
        asm volatile("ds_read_b64_tr_b16 %0, %2\n\t"
                     "ds_read_b64_tr_b16 %1, %2 offset:128"
                     : "=v"(_bl0), "=v"(_bh0) : "v"(_bb));
        asm volatile("ds_read_b64_tr_b16 %0, %2 offset:1024\n\t"
                     "ds_read_b64_tr_b16 %1, %2 offset:1152"
                     : "=v"(_bl1), "=v"(_bh1) : "v"(_bb));
        asm volatile("s_waitcnt lgkmcnt(0)" ::: "memory");
        __builtin_amdgcn_sched_barrier(0);
        s8v _b0, _b1;
        _b0[0]=_bl0[0]; _b0[1]=_bl0[1]; _b0[2]=_bl0[2]; _b0[3]=_bl0[3];
        _b0[4]=_bh0[0]; _b0[5]=_bh0[1]; _b0[6]=_bh0[2]; _b0[7]=_bh0[3];
        _b1[0]=_bl1[0]; _b1[1]=_bl1[1]; _b1[2]=_bl1[2]; _b1[3]=_bl1[3];
        _b1[4]=_bh1[0]; _b1[5]=_bh1[1]; _b1[6]=_bh1[2]; _b1[7]=_bh1[3];
        acc[0][0] = __builtin_amdgcn_mfma_f32_16x16x32_bf16(_a0, _b0, acc[0][0], 0, 0, 0);
        acc[0][1] = __builtin_amdgcn_mfma_f32_16x16x32_bf16(_a0, _b1, acc[0][1], 0, 0, 0);
        acc[1][0] = __builtin_amdgcn_mfma_f32_16x16x32_bf16(_a1, _b0, acc[1][0], 0, 0, 0);
        acc[1][1] = __builtin_amdgcn_mfma_f32_16x16x32_bf16(_a1, _b1, acc[1][1], 0, 0, 0);
        acc[2][0] = __builtin_amdgcn_mfma_f32_16x16x32_bf16(_a2, _b0, acc[2][0], 0, 0, 0);
        acc[2][1] = __builtin_amdgcn_mfma_f32_16x16x32_bf16(_a2, _b1, acc[2][1], 0, 0, 0);
        acc[3][0] = __builtin_amdgcn_mfma_f32_16x16x32_bf16(_a3, _b0, acc[3][0], 0, 0, 0);
        acc[3][1] = __builtin_amdgcn_mfma_f32_16x16x32_bf16(_a3, _b1, acc[3][1], 0, 0, 0);
    }
#undef FC1_BODY
#undef STAGE_A
#undef GBP
#undef BWRITE

    // epilogue: bf16 partial write
    ushort* dst = partb + (size_t)s * 524288 + n0 + wn * 32 + fr;
    #pragma unroll
    for (int mi = 0; mi < 4; ++mi)
        #pragma unroll
        for (int ni = 0; ni < 2; ++ni)
            #pragma unroll
            for (int i = 0; i < 4; ++i) {
                int row = wm * 64 + mi * 16 + fg * 4 + i;
                dst[(size_t)row * 2048 + ni * 16] = f2bf(acc[mi][ni][i]);
            }
}

// ---------------- fc1 reduce: bf16 partials -> h1b (bf16 fragment-linear) + bias + relu ----
// h1b[kg*8192 + (m>>4)*512 + ((k>>3)&3)*128 + (m&15)*8 + (k&7)], kg = k>>5
__global__ void k_reduce_bf(const ushort* __restrict__ part, const float* __restrict__ bias,
                            ushort* __restrict__ h1b) {
    int idx = blockIdx.x * 256 + threadIdx.x;   // 65536 threads, 8 outputs each
    if (idx >= 65536) return;
    int m = idx >> 8;
    int ko = idx & 255;                         // k-octet
    int kbase = ko * 8;
    float s[8];
    #pragma unroll
    for (int j = 0; j < 8; ++j) s[j] = bias[kbase + j];
    #pragma unroll
    for (int i = 0; i < 8; ++i) {
        s8v v = *(const s8v*)(part + (size_t)i * 524288 + (size_t)m * 2048 + kbase);
        #pragma unroll
        for (int j = 0; j < 8; ++j) s[j] += bf2f((ushort)v[j]);
    }
    ushort o[8];
    #pragma unroll
    for (int j = 0; j < 8; ++j) o[j] = f2bf(fmaxf(s[j], 0.f));
    size_t dst = (size_t)(ko >> 2) * 8192 + (m >> 4) * 512 + (ko & 3) * 128 + (m & 15) * 8;
    *(s8v*)(h1b + dst) = *(s8v*)o;
}

// ---------------- FC2: bf16 MFMA; A = h1b fragment-linear (direct loads), B = w2 ----
// M=256, K=2048 (64 kg), N=512. grid (s=8, nblk=8); 8 steps/block.
__global__ __launch_bounds__(512) void fc2_mfma(const ushort* __restrict__ h1b,
                                                const float* __restrict__ w2,
                                                ushort* __restrict__ partb2) {
    __shared__ __align__(16) ushort Bbf[2][2048];
    const int s = blockIdx.x, nblk = blockIdx.y;
    const int n0 = nblk * 64;
    const int k0 = s * 256;                      // k chunk = 256 = 8 steps of 32
    const int tid = threadIdx.x;
    const int lane = tid & 63, w = tid >> 6;
    const int wm = w & 3, wn = w >> 2;
    const int fr = lane & 15, fg = lane >> 4;

    const ushort* gA = h1b + (size_t)s * 8 * 8192;

    const int kr = (w >> 2) * 16 + (lane >> 2);
    const int bnb = w & 3, bnq = lane & 3;
    const int ncol = n0 + bnb * 16 + bnq * 4;
    const int bw_u = bnb * 512 + kr * 16 + bnq * 4;

    const int aoff = wm * 2048 + fg * 128 + fr * 8;
    f4v acc[4][2];
    #pragma unroll
    for (int i = 0; i < 4; ++i)
        #pragma unroll
        for (int j = 0; j < 2; ++j) acc[i][j] = (f4v){0.f, 0.f, 0.f, 0.f};

#define GBP2(t) (*(const float4*)(w2 + (size_t)(k0 + (t) * 32 + kr) * 512 + ncol))
#define BWRITE2(buf, rb) do {                                                                   \
    s4v _u; _u[0] = (short)f2bf((rb).x); _u[1] = (short)f2bf((rb).y);                           \
    _u[2] = (short)f2bf((rb).z); _u[3] = (short)f2bf((rb).w);                                   \
    *(s4v*)&Bbf[buf][bw_u] = _u;                                                                \
} while (0)

    s8v aA0, aA1, aA2, aA3, aB0, aB1, aB2, aB3;
    float4 rb0, rb1, rb2, rb3;

    aA0 = *(const s8v*)(gA + aoff);
    aA1 = *(const s8v*)(gA + aoff + 512);
    aA2 = *(const s8v*)(gA + aoff + 1024);
    aA3 = *(const s8v*)(gA + aoff + 1536);
    rb0 = GBP2(0); rb1 = GBP2(1); rb2 = GBP2(2); rb3 = GBP2(3);
    BWRITE2(0, rb0);
    __syncthreads();

#define FC2_BODY(t, rbL, rbU, aC0, aC1, aC2, aC3, aN0, aN1, aN2, aN3) do {                      \
    int kg1 = (t) + 1 > 7 ? 7 : (t) + 1;                                                        \
    int kg4 = (t) + 4 > 7 ? 7 : (t) + 4;                                                        \
    const ushort* _gn = gA + (size_t)kg1 * 8192;                                                \
    aN0 = *(const s8v*)(_gn + aoff);                                                            \
    aN1 = *(const s8v*)(_gn + aoff + 512);                                                      \
    aN2 = *(const s8v*)(_gn + aoff + 1024);                                                     \
    aN3 = *(const s8v*)(_gn + aoff + 1536);                                                     \
    rbL = GBP2(kg4);                                                                            \
    unsigned _bb = (unsigned)(size_t)(&Bbf[(t) & 1][0]) + wn * 2048 + fg * 256 + fr * 2;        \
    s4v _bl0, _bh0, _bl1, _bh1;                                                                 \
    asm volatile("ds_read_b64_tr_b16 %0, %2\n\t"                                                \
                 "ds_read_b64_tr_b16 %1, %2 offset:128"                                         \
                 : "=v"(_bl0), "=v"(_bh0) : "v"(_bb));                                          \
    asm volatile("ds_read_b64_tr_b16 %0, %2 offset:1024\n\t"                                    \
                 "ds_read_b64_tr_b16 %1, %2 offset:1152"                                        \
                 : "=v"(_bl1), "=v"(_bh1) : "v"(_bb));                                          \
    asm volatile("s_waitcnt lgkmcnt(0)" ::: "memory");                                          \
    __builtin_amdgcn_sched_barrier(0);                                                          \
    s8v _b0, _b1;                                                                               \
    _b0[0]=_bl0[0]; _b0[1]=_bl0[1]; _b0[2]=_bl0[2]; _b0[3]=_bl0[3];                             \
    _b0[4]=_bh0[0]; _b0[5]=_bh0[1]; _b0[6]=_bh0[2]; _b0[7]=_bh0[3];                             \
    _b1[0]=_bl1[0]; _b1[1]=_bl1[1]; _b1[2]=_bl1[2]; _b1[3]=_bl1[3];                             \
    _b1[4]=_bh1[0]; _b1[5]=_bh1[1]; _b1[6]=_bh1[2]; _b1[7]=_bh1[3];                             \
    acc[0][0] = __builtin_amdgcn_mfma_f32_16x16x32_bf16(aC0, _b0, acc[0][0], 0, 0, 0);          \
    acc[0][1] = __builtin_amdgcn_mfma_f32_16x16x32_bf16(aC0, _b1, acc[0][1], 0, 0, 0);          \
    acc[1][0] = __builtin_amdgcn_mfma_f32_16x16x32_bf16(aC1, _b0, acc[1][0], 0, 0, 0);          \
    acc[1][1] = __builtin_amdgcn_mfma_f32_16x16x32_bf16(aC1, _b1, acc[1][1], 0, 0, 0);          \
    acc[2][0] = __builtin_amdgcn_mfma_f32_16x16x32_bf16(aC2, _b0, acc[2][0], 0, 0, 0);          \
    acc[2][1] = __builtin_amdgcn_mfma_f32_16x16x32_bf16(aC2, _b1, acc[2][1], 0, 0, 0);          \
    acc[3][0] = __builtin_amdgcn_mfma_f32_16x16x32_bf16(aC3, _b0, acc[3][0], 0, 0, 0);          \
    acc[3][1] = __builtin_amdgcn_mfma_f32_16x16x32_bf16(aC3, _b1, acc[3][1], 0, 0, 0);          \
    BWRITE2(((t) + 1) & 1, rbU);                                                                \
    __syncthreads();                                                                            \
} while (0)

    FC2_BODY(0, rb0, rb1, aA0, aA1, aA2, aA3, aB0, aB1, aB2, aB3);
    FC2_BODY(1, rb1, rb2, aB0, aB1, aB2, aB3, aA0, aA1, aA2, aA3);
    FC2_BODY(2, rb2, rb3, aA0, aA1, aA2, aA3, aB0, aB1, aB2, aB3);
    FC2_BODY(3, rb3, rb0, aB0, aB1, aB2, aB3, aA0, aA1, aA2, aA3);
    FC2_BODY(4, rb0, rb1, aA0, aA1, aA2, aA3, aB0, aB1, aB2, aB3);
    FC2_BODY(5, rb1, rb2, aB0, aB1, aB2, aB3, aA0, aA1, aA2, aA3);
    FC2_BODY(6, rb2, rb3, aA0, aA1, aA2, aA3, aB0, aB1, aB2, aB3);

    // final step t=7 (odd -> frags in aB), Bbf[1]
    {
        unsigned _bb = (unsigned)(size_t)(&Bbf[1][0]) + wn * 2048 + fg * 256 + fr * 2;
        s4v _bl0, _bh0, _bl1, _bh1;
        asm volatile("ds_read_b64_tr_b16 %0, %2\n\t"
                     "ds_read_b64_tr_b16 %1, %2 offset:128"
                     : "=v"(_bl0), "=v"(_bh0) : "v"(_bb));
        asm volatile("ds_read_b64_tr_b16 %0, %2 offset:1024\n\t"
                     "ds_read_b64_tr_b16 %1, %2 offset:1152"
                     : "=v"(_bl1), "=v"(_bh1) : "v"(_bb));
        asm volatile("s_waitcnt lgkmcnt(0)" ::: "memory");
        __builtin_amdgcn_sched_barrier(0);
        s8v _b0, _b1;
        _b0[0]=_bl0[0]; _b0[1]=_bl0[1]; _b0[2]=_bl0[2]; _b0[3]=_bl0[3];
        _b0[4]=_bh0[0]; _b0[5]=_bh0[1]; _b0[6]=_bh0[2]; _b0[7]=_bh0[3];
        _b1[0]=_bl1[0]; _b1[1]=_bl1[1]; _b1[2]=_bl1[2]; _b1[3]=_bl1[3];
        _b1[4]=_bh1[0]; _b1[5]=_bh1[1]; _b1[6]=_bh1[2]; _b1[7]=_bh1[3];
        acc[0][0] = __builtin_amdgcn_mfma_f32_16x16x32_bf16(aB0, _b0, acc[0][0], 0, 0, 0);
        acc[0][1] = __builtin_amdgcn_mfma_f32_16x16x32_bf16(aB0, _b1, acc[0][1], 0, 0, 0);
        acc[1][0] = __builtin_amdgcn_mfma_f32_16x16x32_bf16(aB1, _b0, acc[1][0], 0, 0, 0);
        acc[1][1] = __builtin_amdgcn_mfma_f32_16x16x32_bf16(aB1, _b1, acc[1][1], 0, 0, 0);
        acc[2][0] = __builtin_amdgcn_mfma_f32_16x16x32_bf16(aB2, _b0, acc[2][0], 0, 0, 0);
        acc[2][1] = __builtin_amdgcn_mfma_f32_16x16x32_bf16(aB2, _b1, acc[2][1], 0, 0, 0);
        acc[3][0] = __builtin_amdgcn_mfma_f32_16x16x32_bf16(aB3, _b0, acc[3][0], 0, 0, 0);
        acc[3][1] = __builtin_amdgcn_mfma_f32_16x16x32_bf16(aB3, _b1, acc[3][1], 0, 0, 0);
    }
#undef FC2_BODY
#undef GBP2
#undef BWRITE2

    ushort* dst = partb2 + (size_t)s * 131072 + n0 + wn * 32 + fr;
    #pragma unroll
    for (int mi = 0; mi < 4; ++mi)
        #pragma unroll
        for (int ni = 0; ni < 2; ++ni)
            #pragma unroll
            for (int i = 0; i < 4; ++i) {
                int row = wm * 64 + mi * 16 + fg * 4 + i;
                dst[(size_t)row * 512 + ni * 16] = f2bf(acc[mi][ni][i]);
            }
}

// ---------------- fc2 reduce: bf16 partials -> h2 fp32 + bias + relu ----------------
__global__ void k_reduce_bf2(const ushort* __restrict__ part, const float* __restrict__ bias,
                             float* __restrict__ h2) {
    int idx = blockIdx.x * 256 + threadIdx.x;   // 16384 threads, 8 outputs each
    if (idx >= 16384) return;
    int m = idx >> 6;
    int no = idx & 63;
    int nbase = no * 8;
    float s[8];
    #pragma unroll
    for (int j = 0; j < 8; ++j) s[j] = bias[nbase + j];
    #pragma unroll
    for (int i = 0; i < 8; ++i) {
        s8v v = *(const s8v*)(part + (size_t)i * 131072 + (size_t)m * 512 + nbase);
        #pragma unroll
        for (int j = 0; j < 8; ++j) s[j] += bf2f((ushort)v[j]);
    }
    float* o = h2 + (size_t)m * 512 + nbase;
    #pragma unroll
    for (int j = 0; j < 8; ++j) o[j] = fmaxf(s[j], 0.f);
}

// ---------------- fc3 fused ----------------
__global__ __launch_bounds__(256) void fc3_small(const float* __restrict__ h2,
                                                 const float* __restrict__ wp,
                                                 const float* __restrict__ bp,
                                                 float* __restrict__ bbox) {
    __shared__ float sh2[8][512];
    int blk = blockIdx.x;
    int tid = threadIdx.x;
    int n = tid & 63;
    int mr = tid >> 6;
    int m0 = blk * 8;
    for (int i = tid; i < 8 * 512; i += 256)
        sh2[i >> 9][i & 511] = h2[(size_t)(m0 + (i >> 9)) * 512 + (i & 511)];
    __syncthreads();
    float b = bp[n];
    float acc0 = b, acc1 = b;
    for (int k = 0; k < 512; ++k) {
        float wv = wp[k * 64 + n];
        acc0 += sh2[mr][k] * wv;
        acc1 += sh2[mr + 4][k] * wv;
    }
    bbox[(size_t)(m0 + mr) * 64 + n] = acc0;
    bbox[(size_t)(m0 + mr + 4) * 64 + n] = acc1;
}

extern "C" void kernel_launch(void* const* d_in, const int* in_sizes, int n_in,
                              void* d_out, int out_size, void* d_ws, size_t ws_size,
                              hipStream_t stream) {
    const float* base   = (const float*)d_in[0];
    const float* tubes  = (const float*)d_in[1];
    const float* conv_w = (const float*)d_in[4];
    const float* conv_b = (const float*)d_in[5];
    const float* w1     = (const float*)d_in[6];
    const float* b1     = (const float*)d_in[7];
    const float* w2     = (const float*)d_in[8];
    const float* b2     = (const float*)d_in[9];
    const float* wp     = (const float*)d_in[10];
    const float* bp     = (const float*)d_in[11];

    float* out    = (float*)d_out;
    float* bbox   = out;
    float* pooled = out + 16384;
    float* rois   = out + 16384 + 3211264;

    float* ws      = (float*)d_ws;
    float* inv     = ws;                         // 12544
    float* partial = ws + 12544;                 // 100352
    float* tsum    = ws + 112896;                // 200704
    float* pooledT = ws + 313600;                // 3211264
    ushort* xb     = (ushort*)(ws + 3524864);    // 6.4MB region
    ushort* h1b    = (ushort*)(ws + 6736128);    // 524288 ushorts (1MB in 2MB slot)
    float* h2      = ws + 7260416;               // 131072
    float* part    = ws + 7391488;               // 16MB region
    ushort* partb  = (ushort*)part;              // fc1 bf16 partials: 8 x 524288 us = 8MB
    ushort* partb2 = (ushort*)(part + 2097152);  // fc2 bf16 partials: 8 x 131072 us = 2MB

    k_sumsq<<<BB * TT * 8, 256, 0, stream>>>(base, partial);
    k_finish_inv<<<49, 256, 0, stream>>>(partial, inv);
    k_tsum<<<BB * CC, 256, 0, stream>>>(base, inv, tsum);
    k_roialign<<<NROI, 256, 0, stream>>>(tubes, tsum, pooled, pooledT, rois);

    conv_mfma<<<dim3(49, 4), 512, 0, stream>>>(pooledT, conv_w, conv_b, xb);

    fc1_mfma<<<dim3(8, 32), 512, 0, stream>>>(xb, w1, partb);
    k_reduce_bf<<<256, 256, 0, stream>>>(partb, b1, h1b);

    fc2_mfma<<<dim3(8, 8), 512, 0, stream>>>(h1b, w2, partb2);
    k_reduce_bf2<<<64, 256, 0, stream>>>(partb2, b2, h2);

    fc3_small<<<32, 256, 0, stream>>>(h2, wp, bp, bbox);
}